// Round 8
// baseline (844.629 us; speedup 1.0000x reference)
//
#include <hip/hip_runtime.h>
#include <stdint.h>

#define B_   128
#define T_   500
#define C_   700
#define CP_  704          // C padded to 16
#define H_   1024
#define O_   20
#define M_   (T_ * B_)    // 64000 rows, row = t*128 + b
#define KA_  (2 * CP_)    // 1408: A' = [hi | lo]
#define KB_  (3 * CP_)    // 2112: Bt = [hi | hi | lo]
#define NKSTEP_ (KB_ / 64)   // 33 K-steps of 64
#define SCALE_      256.0f
#define INV_SCALE2_ (1.0f / 65536.0f)
#define MAXD_ 30
#define TT_   20                       // t-rows produced per delay block
#define RR_   (TT_ + MAXD_)            // 50 source rows staged in LDS
#define CS_   176                      // channels per delay block (4-way split)
#define LSTR_ 180                      // LDS row stride

typedef _Float16 half8 __attribute__((ext_vector_type(8)));
typedef float    f32x4 __attribute__((ext_vector_type(4)));

// ---------------------------------------------------------------------------
// out[c*R + r] = (c < C) ? in[r*C + c] : 0   (fp32 transpose, zero-pad)
__global__ __launch_bounds__(256) void transpose_pad(
    const float* __restrict__ in, float* __restrict__ out,
    int R, int C, int Cpad) {
  int idx = blockIdx.x * 256 + threadIdx.x;
  if (idx >= Cpad * R) return;
  int c = idx / R;
  int r = idx - c * R;
  out[idx] = (c < C) ? in[(size_t)r * C + c] : 0.0f;
}

// ---------------------------------------------------------------------------
// Bt[n][k]: k in [0,704) -> hi(w*256); [704,1408) -> hi; [1408,2112) -> lo
__global__ __launch_bounds__(256) void bt_prep(
    const float* __restrict__ w_in, _Float16* __restrict__ Bt) {
  int idx = blockIdx.x * 256 + threadIdx.x;   // over H_*KB_
  if (idx >= H_ * KB_) return;
  int n = idx / KB_;
  int k = idx - n * KB_;
  int blk = k / CP_;
  int c = k - blk * CP_;
  float v = (c < C_) ? w_in[(size_t)n * C_ + c] * SCALE_ : 0.0f;
  _Float16 hi = (_Float16)v;
  Bt[idx] = (blk == 2) ? (_Float16)(v - (float)hi) : hi;
}

// ---------------------------------------------------------------------------
// R14 delay gather (FROZEN, control).
__global__ __launch_bounds__(512) void delay_split_lds(
    const float* __restrict__ x, const int* __restrict__ delays,
    _Float16* __restrict__ A3) {
  extern __shared__ float xs[];          // [RR_][LSTR_] floats = 36000 B
  __shared__ int sdel[CS_];

  const int id   = blockIdx.x;           // 0..12799
  const int v    = (id & 7) * 1600 + (id >> 3);
  const int ttb  = v % 25;               // t-tile
  const int rest = v / 25;
  const int b    = rest >> 2;            // 0..127
  const int t0   = ttb * TT_;            // 0,20,...,480
  const int c0   = (rest & 3) * CS_;     // 0,176,352,528
  const int tid  = threadIdx.x;

  for (int c = tid; c < CS_; c += 512) {
    const int cc = c0 + c;
    sdel[c] = (cc < C_) ? delays[cc] : 0;
  }

  const int zr = (t0 < MAXD_) ? (MAXD_ - t0) : 0;
  const float* srcb = x + ((long)(b * T_ + t0) - MAXD_) * C_ + c0;
  for (int i = tid; i < RR_ * (CS_ / 4); i += 512) {
    const int r  = i / (CS_ / 4);
    const int q4 = (i - r * (CS_ / 4)) * 4;
    float4 vv = {0.f, 0.f, 0.f, 0.f};
    if (r >= zr && c0 + q4 < C_)
      vv = *(const float4*)(srcb + (long)r * C_ + q4);
    *(float4*)&xs[r * LSTR_ + q4] = vv;
  }
  __syncthreads();

  for (int e = tid; e < TT_ * (CS_ / 8); e += 512) {
    const int tt = e / (CS_ / 8);
    const int cl = (e - tt * (CS_ / 8)) * 8;
    half8 hv, lv;
#pragma unroll
    for (int j = 0; j < 8; ++j) {
      const int c = cl + j;
      float vv = 0.f;
      if (c0 + c < C_)
        vv = xs[(tt + MAXD_ - sdel[c]) * LSTR_ + c] * SCALE_;
      const _Float16 hi = (_Float16)vv;
      hv[j] = hi;
      lv[j] = (_Float16)(vv - (float)hi);
    }
    _Float16* dst = A3 + (size_t)((t0 + tt) * B_ + b) * KA_ + c0 + cl;
    *(half8*)dst = hv;
    *((half8*)(dst + CP_)) = lv;
  }
}

// ---------------------------------------------------------------------------
__device__ __forceinline__ void gload16(const void* g, const void* l) {
  __builtin_amdgcn_global_load_lds(
      (const __attribute__((address_space(1))) void*)(uintptr_t)g,
      (__attribute__((address_space(3))) void*)(uint32_t)(uintptr_t)l,
      16, 0, 0);
}

// ---------------------------------------------------------------------------
// R15 GEMM: 4-phase schedule with frag-reads PIPELINED ONE PHASE AHEAD.
// R11 measured strict LDS<->MFMA pipe alternation (5230 cyc/K-tile/CU =
// 2483 MFMA + 2304 LDS + overhead, MfmaUtil 43.5%): each phase read its OWN
// frags -> all waves read, barrier, all MFMA. Now each phase slot issues the
// NEXT phase's ds_reads (second reg set), then MFMAs frags read one slot
// earlier -> read latency + LDS pipe time hide under the MFMA region.
// Per-tile schedule (cbuf=read buf, nbuf=stage buf):
//  entry: aC=a[m0-3]ks0, b0=b[ks0]  (read at end of prev tile from nbuf)
//  P0: read aN=a[m4-7]ks0 | stage A(k+1)x4 | BAR | MFMA(aC,b0)->acc[0-3] | BAR
//  P1: read aC=a[m0-3]ks1, b1=b[ks1] | stage B h0 | BAR | MFMA(aN,b0)->acc[4-7] | BAR
//  P2: read aN=a[m4-7]ks1 | stage B h1 | BAR | MFMA(aC,b1)->acc[0-3] | BAR
//  P3: vmcnt(0) | BAR | MFMA(aN,b1)->acc[4-7] | read aC,b0 from NBUF (next
//      tile P0; legal: after the barrier that followed every wave's vmcnt(0),
//      nbuf is fully staged and nobody writes it until next tile's stage
//      targets the other buffer) | BAR
// Reg hazards: each ds_read overwriting a frag set is emitted AFTER the MFMA
// cluster that consumed it (same-wave in-order issue); sched_barrier(0)
// around each s_barrier pins slot boundaries. Raw s_barrier does NOT drain
// lgkm, so reads issued pre-barrier stay in flight across it (the point).
__global__ __launch_bounds__(512, 1) void gemm_split(
    const _Float16* __restrict__ A3, const _Float16* __restrict__ Bt,
    float* __restrict__ Cm) {
  extern __shared__ __align__(16) _Float16 lds[];   // 131072 B
  _Float16* As = lds;                // [2][256*64]
  _Float16* Bs = lds + 2 * 16384;    // [2][256*64]

  const int tid  = threadIdx.x;
  const int wave = tid >> 6, lane = tid & 63;

  const int d = blockIdx.x;
  const int g = (d & 7) * 125 + (d >> 3);
  const int row0 = (g >> 2) * 256;        // M panel (0..249)
  const int col0 = (g & 3) * 256;         // N panel (0..3)

  const int r = lane & 15, q = lane >> 4;
  const int wm = wave >> 2, wn = wave & 3;

  int asrcB[4], bsrcB[4], auoff[4];
#pragma unroll
  for (int j = 0; j < 4; ++j) {
    const int i   = j * 512 + wave * 64 + lane;
    const int row = i >> 3, c = i & 7;
    asrcB[j] = (row0 + row) * KA_ + ((c ^ (row & 7)) * 8);
    bsrcB[j] = (col0 + row) * KB_ + ((c ^ (row & 7)) * 8);
    auoff[j] = (j * 512 + wave * 64) * 8;   // wave-uniform LDS base (halfs)
  }

  int aRow[8], bRow[4];
#pragma unroll
  for (int m = 0; m < 8; ++m) aRow[m] = (wm * 128 + m * 16 + r) * 64;
#pragma unroll
  for (int n = 0; n < 4; ++n) bRow[n] = (wn * 64 + n * 16 + r) * 64;
  const int sl0 = (q ^ (r & 7)) * 8;      // ks=0 slot
  const int sl1 = sl0 ^ 32;               // ks=1 slot

  f32x4 acc[8][4] = {};

  // prologue: stage K-tile 0 into buf 0, drain, sync
#pragma unroll
  for (int j = 0; j < 4; ++j) gload16(A3 + asrcB[j], As + auoff[j]);
#pragma unroll
  for (int j = 0; j < 4; ++j) gload16(Bt + bsrcB[j], Bs + auoff[j]);
  asm volatile("s_waitcnt vmcnt(0)" ::: "memory");
  __syncthreads();

#define PHASE_BAR() do {                                   \
    __builtin_amdgcn_sched_barrier(0);                     \
    __builtin_amdgcn_s_barrier();                          \
    __builtin_amdgcn_sched_barrier(0);                     \
  } while (0)

#define MFMA16(ACCROW, AF, BF) do {                        \
    __builtin_amdgcn_s_setprio(1);                         \
    _Pragma("unroll")                                      \
    for (int mm = 0; mm < 4; ++mm)                         \
      _Pragma("unroll")                                    \
      for (int nn = 0; nn < 4; ++nn)                       \
        ACCROW[mm][nn] = __builtin_amdgcn_mfma_f32_16x16x32_f16( \
            AF[mm], BF[nn], ACCROW[mm][nn], 0, 0, 0);      \
    __builtin_amdgcn_s_setprio(0);                         \
  } while (0)

  half8 aC[4], aN[4], b0[4], b1[4];
  f32x4 (&accLo)[4][4] = *reinterpret_cast<f32x4(*)[4][4]>(&acc[0]);
  f32x4 (&accHi)[4][4] = *reinterpret_cast<f32x4(*)[4][4]>(&acc[4]);

  // pre-tile reads: aC = a[m0-3]ks0, b0 = b[ks0] from buf 0
#pragma unroll
  for (int m = 0; m < 4; ++m) aC[m] = *(const half8*)&As[aRow[m] + sl0];
#pragma unroll
  for (int n = 0; n < 4; ++n) b0[n] = *(const half8*)&Bs[bRow[n] + sl0];

  for (int k = 0; k < NKSTEP_; ++k) {
    const int cbuf = (k & 1) * 16384;
    const int nbuf = ((k + 1) & 1) * 16384;
    const int k0n  = (k + 1) * 64;
    const int kAn  = (k0n < KA_) ? k0n : k0n - KA_;
    const bool st  = (k + 1 < NKSTEP_);

    // ---- P0 slot: read aN (P1's frags); stage A(k+1); MFMA(aC,b0)
#pragma unroll
    for (int m = 0; m < 4; ++m) aN[m] = *(const half8*)&As[cbuf + aRow[m + 4] + sl0];
    if (st) {
#pragma unroll
      for (int j = 0; j < 4; ++j) gload16(A3 + asrcB[j] + kAn, As + nbuf + auoff[j]);
    }
    PHASE_BAR();
    MFMA16(accLo, aC, b0);
    PHASE_BAR();

    // ---- P1 slot: read aC'=a[m0-3]ks1 + b1 (P2's frags); stage B h0; MFMA(aN,b0)
#pragma unroll
    for (int m = 0; m < 4; ++m) aC[m] = *(const half8*)&As[cbuf + aRow[m] + sl1];
#pragma unroll
    for (int n = 0; n < 4; ++n) b1[n] = *(const half8*)&Bs[cbuf + bRow[n] + sl1];
    if (st) {
      gload16(Bt + bsrcB[0] + k0n, Bs + nbuf + auoff[0]);
      gload16(Bt + bsrcB[1] + k0n, Bs + nbuf + auoff[1]);
    }
    PHASE_BAR();
    MFMA16(accHi, aN, b0);
    PHASE_BAR();

    // ---- P2 slot: read aN'=a[m4-7]ks1 (P3's frags); stage B h1; MFMA(aC,b1)
#pragma unroll
    for (int m = 0; m < 4; ++m) aN[m] = *(const half8*)&As[cbuf + aRow[m + 4] + sl1];
    if (st) {
      gload16(Bt + bsrcB[2] + k0n, Bs + nbuf + auoff[2]);
      gload16(Bt + bsrcB[3] + k0n, Bs + nbuf + auoff[3]);
    }
    PHASE_BAR();
    MFMA16(accLo, aC, b1);
    PHASE_BAR();

    // ---- P3 slot: drain stage; MFMA(aN,b1); read next tile's P0 frags
    asm volatile("s_waitcnt vmcnt(0)" ::: "memory");
    PHASE_BAR();                         // after this, nbuf fully staged
    MFMA16(accHi, aN, b1);
    if (st) {
#pragma unroll
      for (int m = 0; m < 4; ++m) aC[m] = *(const half8*)&As[nbuf + aRow[m] + sl0];
#pragma unroll
      for (int n = 0; n < 4; ++n) b0[n] = *(const half8*)&Bs[nbuf + bRow[n] + sl0];
    }
    PHASE_BAR();
  }
#undef MFMA16
#undef PHASE_BAR

  // epilogue: C write (unchanged layout)
#pragma unroll
  for (int m = 0; m < 8; ++m) {
    const int mrow = row0 + wm * 128 + m * 16 + q * 4;
#pragma unroll
    for (int n = 0; n < 4; ++n) {
      const int ncol = col0 + wn * 64 + n * 16 + r;
      float* cp = Cm + (size_t)mrow * H_ + ncol;
#pragma unroll
      for (int rg = 0; rg < 4; ++rg)
        cp[(size_t)rg * H_] = acc[m][n][rg] * INV_SCALE2_;
    }
  }
}

// ---------------------------------------------------------------------------
// R8 recurrent (FROZEN, control).
#define GATHER_LIF_STEP(NR, TCUR)                                             \
  {                                                                           \
    float Iv[4];                                                              \
    Iv[0] = NR.x; Iv[1] = NR.y; Iv[2] = NR.z; Iv[3] = NR.w;                   \
    float io = 0.f;                                                           \
    unsigned long long lm = __ballot(sword != 0u);                            \
    unsigned w = 0u;                                                          \
    int lcur = 0;                                                             \
    while ((lm != 0ull) | (w != 0u)) {                                        \
      int hA, hB, hC, hD;                                                     \
      float sB, sC, sD;                                                       \
      if (w == 0u) {                                                          \
        lcur = (int)__builtin_ctzll(lm); lm &= lm - 1ull;                     \
        w = ((unsigned)__builtin_amdgcn_readlane((int)sword, lcur)) & 0xFFFFu;\
      }                                                                       \
      hA = lcur * 16 + (int)__builtin_ctz(w); w &= w - 1u;                    \
      if (w == 0u && lm != 0ull) {                                            \
        lcur = (int)__builtin_ctzll(lm); lm &= lm - 1ull;                     \
        w = ((unsigned)__builtin_amdgcn_readlane((int)sword, lcur)) & 0xFFFFu;\
      }                                                                       \
      if (w != 0u) { hB = lcur*16 + (int)__builtin_ctz(w); w &= w-1u; sB=1.f;}\
      else         { hB = hA; sB = 0.f; }                                     \
      if (w == 0u && lm != 0ull) {                                            \
        lcur = (int)__builtin_ctzll(lm); lm &= lm - 1ull;                     \
        w = ((unsigned)__builtin_amdgcn_readlane((int)sword, lcur)) & 0xFFFFu;\
      }                                                                       \
      if (w != 0u) { hC = lcur*16 + (int)__builtin_ctz(w); w &= w-1u; sC=1.f;}\
      else         { hC = hA; sC = 0.f; }                                     \
      if (w == 0u && lm != 0ull) {                                            \
        lcur = (int)__builtin_ctzll(lm); lm &= lm - 1ull;                     \
        w = ((unsigned)__builtin_amdgcn_readlane((int)sword, lcur)) & 0xFFFFu;\
      }                                                                       \
      if (w != 0u) { hD = lcur*16 + (int)__builtin_ctz(w); w &= w-1u; sD=1.f;}\
      else         { hD = hA; sD = 0.f; }                                     \
      const float4 wA = *(const float4*)(wrecT + (size_t)hA * H_ + h0);       \
      const float4 wB = *(const float4*)(wrecT + (size_t)hB * H_ + h0);       \
      const float4 wC = *(const float4*)(wrecT + (size_t)hC * H_ + h0);       \
      const float4 wD = *(const float4*)(wrecT + (size_t)hD * H_ + h0);       \
      const float oA = woutT[(size_t)hA * O_ + olane];                        \
      const float oB = woutT[(size_t)hB * O_ + olane];                        \
      const float oC = woutT[(size_t)hC * O_ + olane];                        \
      const float oD = woutT[(size_t)hD * O_ + olane];                        \
      Iv[0] += wA.x; Iv[1] += wA.y; Iv[2] += wA.z; Iv[3] += wA.w;             \
      io += oA;                                                               \
      Iv[0] = fmaf(sB, wB.x, Iv[0]); Iv[1] = fmaf(sB, wB.y, Iv[1]);           \
      Iv[2] = fmaf(sB, wB.z, Iv[2]); Iv[3] = fmaf(sB, wB.w, Iv[3]);           \
      io = fmaf(sB, oB, io);                                                  \
      Iv[0] = fmaf(sC, wC.x, Iv[0]); Iv[1] = fmaf(sC, wC.y, Iv[1]);           \
      Iv[2] = fmaf(sC, wC.z, Iv[2]); Iv[3] = fmaf(sC, wC.w, Iv[3]);           \
      io = fmaf(sC, oC, io);                                                  \
      Iv[0] = fmaf(sD, wD.x, Iv[0]); Iv[1] = fmaf(sD, wD.y, Iv[1]);           \
      Iv[2] = fmaf(sD, wD.z, Iv[2]); Iv[3] = fmaf(sD, wD.w, Iv[3]);           \
      io = fmaf(sD, oD, io);                                                  \
    }                                                                         \
    {                                                                         \
      const int tp = ((TCUR) + 4 <= T_ - 1) ? (TCUR) + 4 : (T_ - 1);          \
      NR = *(const float4*)(base + (size_t)tp * (B_ * H_));                   \
    }                                                                         \
    vo = bo * vo + (1.0f - bo) * io;                                          \
    osum += vo;                                                               \
    unsigned nib = 0u;                                                        \
    _Pragma("unroll")                                                         \
    for (int j = 0; j < 4; ++j) {                                             \
      const float vg = (pnib & (1u << j)) ? 0.f : vv[j];                      \
      const float vn = al * vg + al1 * (Iv[j] - av[j]);                       \
      av[j] = rh * av[j] + rh1 * fmaf(ba, vn, (vn > 1.0f) ? 1.0f : 0.0f);     \
      vv[j] = vn;                                                             \
      nib |= (vn > 1.0f) ? (1u << j) : 0u;                                    \
    }                                                                         \
    pnib = nib;                                                               \
    spb[nbuf][tid] = (unsigned char)nib;                                      \
    __syncthreads();                                                          \
    {                                                                         \
      const unsigned w32 = *(const unsigned*)&spb[nbuf][lane * 4];            \
      sword = (w32 & 0xFu) | ((w32 >> 4) & 0xF0u) |                           \
              ((w32 >> 8) & 0xF00u) | ((w32 >> 12) & 0xF000u);                \
    }                                                                         \
    nbuf ^= 1;                                                                \
  }

__global__ __launch_bounds__(256, 1) void recurrent_w(
    const float* __restrict__ Iin,   // [M_][H_], row = t*128 + b
    const float* __restrict__ wrecT, // [H_][H_]  wrecT[h'][h] = w_rec[h][h']
    const float* __restrict__ woutT, // [H_][O_]  woutT[h][o]  = w_out[o][h]
    const float* __restrict__ alpha, const float* __restrict__ rho,
    const float* __restrict__ beta_a, const float* __restrict__ beta_out,
    float* __restrict__ out) {
  const int b    = blockIdx.x;
  const int tid  = threadIdx.x;     // 0..255
  const int lane = tid & 63;
  const int h0   = tid * 4;         // 4 columns per thread

  __shared__ unsigned char spb[2][256];   // double-buffered spike nibbles

  float vv[4], av[4];
#pragma unroll
  for (int j = 0; j < 4; ++j) { vv[j] = 0.f; av[j] = 0.f; }
  unsigned sword = 0u;   // full-bitmap slice: bit j = neuron lane*16+j @ prev
  unsigned pnib  = 0u;   // this thread's own 4 prev-spike bits
  int nbuf = 0;

  const float al = alpha[h0], al1 = 1.0f - al;
  const float rh = rho[h0],   rh1 = 1.0f - rh;
  const float ba = beta_a[h0];

  const int olane = (tid < O_) ? tid : 0;
  float bo = 0.f, vo = 0.f, osum = 0.f;
  if (tid < O_) bo = beta_out[tid];

  const float* base = Iin + (size_t)b * H_ + h0;

  // prime 4-deep prefetch pipeline: one float4 per t = 0,1,2,3
  float4 pA = *(const float4*)(base + (size_t)0 * (B_ * H_));
  float4 pB = *(const float4*)(base + (size_t)1 * (B_ * H_));
  float4 pC = *(const float4*)(base + (size_t)2 * (B_ * H_));
  float4 pD = *(const float4*)(base + (size_t)3 * (B_ * H_));

  for (int k = 0; k < T_ / 4; ++k) {
    const int t0 = k * 4;
    GATHER_LIF_STEP(pA, t0 + 0)
    GATHER_LIF_STEP(pB, t0 + 1)
    GATHER_LIF_STEP(pC, t0 + 2)
    GATHER_LIF_STEP(pD, t0 + 3)
  }

  // epilogue: readout contribution of the final spike set S(T-1)
  {
    float io = 0.f;
    unsigned long long lm = __ballot(sword != 0u);
    while (lm != 0ull) {
      const int l = (int)__builtin_ctzll(lm); lm &= lm - 1ull;
      unsigned w = ((unsigned)__builtin_amdgcn_readlane((int)sword, l)) & 0xFFFFu;
      while (w != 0u) {
        const int j = (int)__builtin_ctz(w); w &= w - 1u;
        io += woutT[(size_t)(l * 16 + j) * O_ + olane];
      }
    }
    vo = bo * vo + (1.0f - bo) * io;
    osum += vo;
  }

  if (tid < O_) out[(size_t)b * O_ + tid] = osum / (float)T_;
}

// ---------------------------------------------------------------------------
extern "C" void kernel_launch(void* const* d_in, const int* in_sizes, int n_in,
                              void* d_out, int out_size, void* d_ws, size_t ws_size,
                              hipStream_t stream) {
  const float* x        = (const float*)d_in[0];
  const int*   delays   = (const int*)d_in[1];
  const float* w_in     = (const float*)d_in[2];
  const float* w_rec    = (const float*)d_in[3];
  const float* w_out    = (const float*)d_in[4];
  const float* alpha    = (const float*)d_in[5];
  const float* rho      = (const float*)d_in[6];
  const float* beta_a   = (const float*)d_in[7];
  const float* beta_out = (const float*)d_in[8];

  float* ws    = (float*)d_ws;
  float* wrecT = ws;                                 // H*H fp32
  float* woutT = wrecT + (size_t)H_ * H_;            // H*O fp32
  float* Iin   = woutT + (size_t)H_ * O_;            // M*H fp32
  _Float16* A3 = (_Float16*)(Iin + (size_t)M_ * H_); // M*KA fp16
  _Float16* Bt = A3 + (size_t)M_ * KA_;              // H*KB fp16
  float* out   = (float*)d_out;

  transpose_pad<<<(H_ * H_) / 256, 256, 0, stream>>>(w_rec, wrecT, H_, H_, H_);
  transpose_pad<<<(H_ * O_) / 256, 256, 0, stream>>>(w_out, woutT, O_, H_, H_);
  bt_prep<<<(H_ * KB_) / 256, 256, 0, stream>>>(w_in, Bt);

  // 1D grid with XCD-locality remap inside the kernel (12800 = 128*25*4)
  delay_split_lds<<<12800, 512, RR_ * LSTR_ * sizeof(float), stream>>>(
      x, delays, A3);

  // 256x256 tiles: (64000/256) * (1024/256) = 250 * 4 = 1000 blocks
  gemm_split<<<1000, 512, 131072, stream>>>(A3, Bt, Iin);

  recurrent_w<<<B_, 256, 0, stream>>>(Iin, wrecT, woutT,
                                      alpha, rho, beta_a, beta_out, out);
}